// Round 12
// baseline (84.573 us; speedup 1.0000x reference)
//
#include <hip/hip_runtime.h>
#include <math.h>

// Problem constants (fixed by setup_inputs)
#define BB 4
#define NIC 64
#define CC 64
#define HH 256
#define WW 256
#define HW (HH * WW)

#define SRW 68          // K2 strip row stride (66 used)
#define BUFW 272        // K2: 4 rows * 68 floats

typedef short sh8 __attribute__((ext_vector_type(8)));    // 8 x bf16 MFMA frag
typedef float f32x4 __attribute__((ext_vector_type(4)));  // MFMA accum

// numpy/jax "reflect" (mirror, edge not repeated), pad=1
__device__ __forceinline__ int refl(int i, int n) {
    i = (i < 0) ? -i : i;
    return (i >= n) ? (2 * n - 2 - i) : i;
}
// fp32 -> bf16 round-to-nearest-even
__device__ __forceinline__ unsigned short f2bf(float v) {
    unsigned int x = __builtin_bit_cast(unsigned int, v);
    return (unsigned short)((x + 0x7FFFu + ((x >> 16) & 1u)) >> 16);
}

// ---- prep: weight A-fragments into d_ws (verified R11) ----------------------
__global__ void pff_prep(const float* __restrict__ wgt, uint4* __restrict__ wtab) {
    int e = blockIdx.x * 256 + threadIdx.x;
    if (e >= 1152) return;
    const int c = e >> 6, l = e & 63;
    const int p = c / 9, s = c - p * 9;
    const int tap = l & 15, kg = l >> 4;
    unsigned short h[8];
    #pragma unroll
    for (int j = 0; j < 8; ++j) {
        const int ni = 32 * p + 8 * kg + j;
        const float v = (tap <= 8) ? wgt[tap * 576 + ni * 9 + s] : 0.f;
        h[j] = f2bf(v);
    }
    uint4 o;
    o.x = h[0] | ((unsigned)h[1] << 16);
    o.y = h[2] | ((unsigned)h[3] << 16);
    o.z = h[4] | ((unsigned)h[5] << 16);
    o.w = h[6] | ((unsigned)h[7] << 16);
    wtab[e] = o;
}

// ---- K1: conv + softmax -> ff[b][9][H][W] fp32 ------------------------------
// Tile 32w x 8h, 512 threads (8 waves); wave wv owns px row wv, 2 groups of
// 16 px. Features staged bf16 [10r][34c][32ni] (cell stride 34 shorts ->
// odd dword multiplier, near-conflict-free). 2 K-passes of 32 ni.
// LDS 23 KB -> 4 blocks/CU (32 waves/CU). Softmax in-reg (verified R11).
__global__ __launch_bounds__(512) void pff_conv(
    const float* __restrict__ features,
    const float* __restrict__ bias,
    const uint4* __restrict__ wtab,
    float* __restrict__ ff)
{
    __shared__ unsigned short FT[10 * 34 * 34];   // 23120 B

    const int tid = threadIdx.x;
    const int wv  = __builtin_amdgcn_readfirstlane(tid >> 6);  // 0..7
    const int l   = tid & 63;
    const int pxl = l & 15, kg = l >> 4;
    const int W0 = blockIdx.x * 32, H0 = blockIdx.y * 8, b = blockIdx.z;

    // staging offsets (pass-invariant): 5440 packed b32 per pass, 11/thread
    int stg_g[11], stg_l[11];
    #pragma unroll
    for (int i = 0; i < 11; ++i) {
        const int flat = tid + 512 * i;
        const int nip = flat / 340;
        const int rc  = flat - nip * 340;
        const int r   = rc / 34, c2 = rc - r * 34;
        stg_l[i] = (flat < 5440) ? ((r * 34 + c2) * 34 + 2 * nip) : -1;
        stg_g[i] = refl(H0 - 1 + r, HH) * WW + refl(W0 - 1 + c2, WW)
                 + 2 * nip * HW;
    }

    f32x4 acc[2];
    acc[0] = (f32x4){0.f, 0.f, 0.f, 0.f};
    acc[1] = (f32x4){0.f, 0.f, 0.f, 0.f};

    #pragma unroll
    for (int p = 0; p < 2; ++p) {
        uint4 wf[9];   // weight frags: issued early, used after barrier
        #pragma unroll
        for (int s = 0; s < 9; ++s) wf[s] = wtab[(p * 9 + s) * 64 + l];

        const float* fp0 = features + ((size_t)b * NIC + 32 * p) * HW;
        #pragma unroll
        for (int i = 0; i < 11; ++i) {
            if (stg_l[i] >= 0) {
                const float* fp = fp0 + stg_g[i];
                const unsigned pk = f2bf(fp[0]) | ((unsigned)f2bf(fp[HW]) << 16);
                *(unsigned*)&FT[stg_l[i]] = pk;
            }
        }
        __syncthreads();   // tile pass p ready

        #pragma unroll
        for (int g = 0; g < 2; ++g) {
            #pragma unroll
            for (int s = 0; s < 9; ++s) {
                const int di = s / 3, dj = s - di * 3;
                const unsigned* q = (const unsigned*)
                    &FT[((wv + di) * 34 + pxl + 16 * g + dj) * 34 + kg * 8];
                uint4 bw;
                bw.x = q[0]; bw.y = q[1]; bw.z = q[2]; bw.w = q[3];
                acc[g] = __builtin_amdgcn_mfma_f32_16x16x32_bf16(
                    __builtin_bit_cast(sh8, wf[s]),
                    __builtin_bit_cast(sh8, bw), acc[g], 0, 0, 0);
            }
        }
        if (p == 0) __syncthreads();   // reads done before pass-1 overwrite
    }

    // softmax per group (taps on lanes pxl+{0,16,32,48}; verified R11)
    float bv4[4];
    #pragma unroll
    for (int j = 0; j < 4; ++j) {
        const int tap = 4 * kg + j;
        bv4[j] = bias[tap <= 8 ? tap : 8];
    }
    #pragma unroll
    for (int g = 0; g < 2; ++g) {
        float lg[4]; bool val[4];
        #pragma unroll
        for (int j = 0; j < 4; ++j) {
            const int tap = 4 * kg + j;
            val[j] = (tap <= 8);
            lg[j] = acc[g][j] + bv4[j];
        }
        float ml = -3e38f;
        #pragma unroll
        for (int j = 0; j < 4; ++j) ml = fmaxf(ml, val[j] ? lg[j] : -3e38f);
        float m = fmaxf(ml, __shfl_xor(ml, 16));
        m = fmaxf(m, __shfl_xor(m, 32));
        float e[4], sl = 0.f;
        #pragma unroll
        for (int j = 0; j < 4; ++j) { e[j] = val[j] ? __expf(lg[j] - m) : 0.f; sl += e[j]; }
        float s = sl + __shfl_xor(sl, 16);
        s += __shfl_xor(s, 32);
        const float inv = 1.f / s;
        #pragma unroll
        for (int j = 0; j < 4; ++j) {
            const int tap = 4 * kg + j;
            if (val[j])
                ff[(size_t)(b * 9 + tap) * HW + (H0 + wv) * WW + W0 + 16 * g + pxl]
                    = e[j] * inv;
        }
    }
}

// ---- K2: apply ff to inpt (R10 P2 standalone, proven) -----------------------
// Block 64w x 4h, 512 thr = 4 ch-quarters x 2 row-waves; wave-private strips,
// barrier-FREE loop, depth-1 prefetch. 17 KB LDS -> 32 waves/CU.
__global__ __launch_bounds__(512) void pff_apply(
    const float* __restrict__ inpt,
    const float* __restrict__ ff,
    float* __restrict__ out)
{
    __shared__ float stage[8][2 * BUFW];      // 17408 B

    const int tid = threadIdx.x;
    const int wv  = __builtin_amdgcn_readfirstlane(tid >> 6);  // 0..7
    const int q   = wv >> 1;                  // ch quarter
    const int tr  = wv & 1;                   // row-wave
    const int l   = tid & 63;
    const int W0 = blockIdx.x * 64;
    const int H0 = blockIdx.y * 4;
    const int b  = blockIdx.z;

    int goff[5], loff[5];
    #pragma unroll
    for (int t = 0; t < 5; ++t) {
        const int e = (t < 4) ? (l + 64 * t) : (256 + (l & 7));
        const int row = e / 66, col = e - row * 66;
        loff[t] = row * SRW + col;
        goff[t] = refl(H0 + 2 * tr - 1 + row, HH) * WW + refl(W0 - 1 + col, WW);
    }
    const bool do5 = (l < 8);

    // per-pixel filters for this wave's two rows
    const int oA = (H0 + 2 * tr) * WW + W0 + l;
    const int oB = oA + WW;
    const float* ffb = ff + (size_t)b * 9 * HW;
    float ffA[9], ffB[9];
    #pragma unroll
    for (int k = 0; k < 9; ++k) { ffA[k] = ffb[k * HW + oA]; ffB[k] = ffb[k * HW + oB]; }

    const float* ip = inpt + ((size_t)b * CC + q * 16) * HW;
    float* ob       = out  + ((size_t)b * CC + q * 16) * HW;
    float* sb = &stage[wv][0];

    float r0 = ip[goff[0]], r1 = ip[goff[1]], r2 = ip[goff[2]], r3 = ip[goff[3]];
    float r4 = do5 ? ip[goff[4]] : 0.f;

    for (int ch = 0; ch < 16; ++ch) {
        float* bw = sb + (ch & 1) * BUFW;
        bw[loff[0]] = r0; bw[loff[1]] = r1; bw[loff[2]] = r2; bw[loff[3]] = r3;
        if (do5) bw[loff[4]] = r4;
        if (ch < 15) {
            const float* in2 = ip + (size_t)(ch + 1) * HW;
            r0 = in2[goff[0]]; r1 = in2[goff[1]]; r2 = in2[goff[2]]; r3 = in2[goff[3]];
            if (do5) r4 = in2[goff[4]];
        }

        float f[12];
        #pragma unroll
        for (int rr = 0; rr < 4; ++rr) {
            const float* br = bw + rr * SRW + l;
            f[rr * 3 + 0] = br[0];
            f[rr * 3 + 1] = br[1];
            f[rr * 3 + 2] = br[2];
        }

        float vA = ffA[0] * f[0];
        float vB = ffB[0] * f[3];
        vA = fmaf(ffA[1], f[1],  vA);  vB = fmaf(ffB[1], f[4],  vB);
        vA = fmaf(ffA[2], f[2],  vA);  vB = fmaf(ffB[2], f[5],  vB);
        vA = fmaf(ffA[3], f[3],  vA);  vB = fmaf(ffB[3], f[6],  vB);
        vA = fmaf(ffA[4], f[4],  vA);  vB = fmaf(ffB[4], f[7],  vB);
        vA = fmaf(ffA[5], f[5],  vA);  vB = fmaf(ffB[5], f[8],  vB);
        vA = fmaf(ffA[6], f[6],  vA);  vB = fmaf(ffB[6], f[9],  vB);
        vA = fmaf(ffA[7], f[7],  vA);  vB = fmaf(ffB[7], f[10], vB);
        vA = fmaf(ffA[8], f[8],  vA);  vB = fmaf(ffB[8], f[11], vB);
        ob[(size_t)ch * HW + oA] = vA;
        ob[(size_t)ch * HW + oB] = vB;
    }
}

// ---- fallback: R10 fused kernel (proven 70 us) if ws too small --------------
__global__ __launch_bounds__(512) void pff_wave4(
    const float* __restrict__ features,
    const float* __restrict__ inpt,
    const float* __restrict__ wgt,
    const float* __restrict__ bias,
    float* __restrict__ out)
{
    __shared__ float stage[8][2 * BUFW];
    __shared__ float part[4][9][128];

    const int tid  = threadIdx.x;
    const int wv   = __builtin_amdgcn_readfirstlane(tid >> 6);
    const int q    = wv >> 1;
    const int tr   = wv & 1;
    const int l    = tid & 63;
    const int p    = tid & 127;
    const int W0 = blockIdx.x * 64;
    const int H0 = blockIdx.y * 4;
    const int b  = blockIdx.z;

    int goff[5], loff[5];
    #pragma unroll
    for (int t = 0; t < 5; ++t) {
        const int e = (t < 4) ? (l + 64 * t) : (256 + (l & 7));
        const int row = e / 66, col = e - row * 66;
        loff[t] = row * SRW + col;
        goff[t] = refl(H0 + 2 * tr - 1 + row, HH) * WW + refl(W0 - 1 + col, WW);
    }
    const bool do5 = (l < 8);

    float accA[9], accB[9];
    #pragma unroll
    for (int k = 0; k < 9; ++k) { accA[k] = 0.f; accB[k] = 0.f; }

    float* sb = &stage[wv][0];
    const float* fb = features + (size_t)b * NIC * HW + (size_t)q * 16 * HW;
    float r0 = fb[goff[0]], r1 = fb[goff[1]], r2 = fb[goff[2]], r3 = fb[goff[3]];
    float r4 = do5 ? fb[goff[4]] : 0.f;

    for (int ni = 0; ni < 16; ++ni) {
        float* bw = sb + (ni & 1) * BUFW;
        bw[loff[0]] = r0; bw[loff[1]] = r1; bw[loff[2]] = r2; bw[loff[3]] = r3;
        if (do5) bw[loff[4]] = r4;
        if (ni < 15) {
            const float* fn = fb + (size_t)(ni + 1) * HW;
            r0 = fn[goff[0]]; r1 = fn[goff[1]]; r2 = fn[goff[2]]; r3 = fn[goff[3]];
            if (do5) r4 = fn[goff[4]];
        }
        float f[12];
        #pragma unroll
        for (int rr = 0; rr < 4; ++rr) {
            const float* br = bw + rr * SRW + l;
            f[rr * 3 + 0] = br[0];
            f[rr * 3 + 1] = br[1];
            f[rr * 3 + 2] = br[2];
        }
        const float* wn = wgt + (q * 16 + ni) * 9;
        #pragma unroll
        for (int k = 0; k < 9; ++k) {
            const float* wk = wn + k * (NIC * 9);
            const float w0 = wk[0], w1 = wk[1], w2 = wk[2];
            const float w3 = wk[3], w4 = wk[4], w5 = wk[5];
            const float w6 = wk[6], w7 = wk[7], w8 = wk[8];
            accA[k] = fmaf(f[0],  w0, accA[k]);
            accB[k] = fmaf(f[3],  w0, accB[k]);
            accA[k] = fmaf(f[1],  w1, accA[k]);
            accB[k] = fmaf(f[4],  w1, accB[k]);
            accA[k] = fmaf(f[2],  w2, accA[k]);
            accB[k] = fmaf(f[5],  w2, accB[k]);
            accA[k] = fmaf(f[3],  w3, accA[k]);
            accB[k] = fmaf(f[6],  w3, accB[k]);
            accA[k] = fmaf(f[4],  w4, accA[k]);
            accB[k] = fmaf(f[7],  w4, accB[k]);
            accA[k] = fmaf(f[5],  w5, accA[k]);
            accB[k] = fmaf(f[8],  w5, accB[k]);
            accA[k] = fmaf(f[6],  w6, accA[k]);
            accB[k] = fmaf(f[9],  w6, accB[k]);
            accA[k] = fmaf(f[7],  w7, accA[k]);
            accB[k] = fmaf(f[10], w7, accB[k]);
            accA[k] = fmaf(f[8],  w8, accA[k]);
            accB[k] = fmaf(f[11], w8, accB[k]);
        }
    }

    const float* ib = inpt + (size_t)b * CC * HW + (size_t)q * 16 * HW;
    r0 = ib[goff[0]]; r1 = ib[goff[1]]; r2 = ib[goff[2]]; r3 = ib[goff[3]];
    if (do5) r4 = ib[goff[4]];

    #pragma unroll
    for (int k = 0; k < 9; ++k) part[q][k][p] = accA[k];
    __syncthreads();
    #pragma unroll
    for (int k = 0; k < 9; ++k)
        accA[k] = part[0][k][p] + part[1][k][p] + part[2][k][p] + part[3][k][p] + bias[k];
    __syncthreads();
    #pragma unroll
    for (int k = 0; k < 9; ++k) part[q][k][p] = accB[k];
    __syncthreads();
    #pragma unroll
    for (int k = 0; k < 9; ++k)
        accB[k] = part[0][k][p] + part[1][k][p] + part[2][k][p] + part[3][k][p] + bias[k];

    {
        float m = accA[0];
        #pragma unroll
        for (int k = 1; k < 9; ++k) m = fmaxf(m, accA[k]);
        float s = 0.f;
        #pragma unroll
        for (int k = 0; k < 9; ++k) { accA[k] = __expf(accA[k] - m); s += accA[k]; }
        const float inv = 1.f / s;
        #pragma unroll
        for (int k = 0; k < 9; ++k) accA[k] *= inv;
    }
    {
        float m = accB[0];
        #pragma unroll
        for (int k = 1; k < 9; ++k) m = fmaxf(m, accB[k]);
        float s = 0.f;
        #pragma unroll
        for (int k = 0; k < 9; ++k) { accB[k] = __expf(accB[k] - m); s += accB[k]; }
        const float inv = 1.f / s;
        #pragma unroll
        for (int k = 0; k < 9; ++k) accB[k] *= inv;
    }

    float* ob = out + (size_t)b * CC * HW + (size_t)q * 16 * HW;
    const int oA = (H0 + 2 * tr) * WW + W0 + l;
    const int oB = oA + WW;
    for (int ch = 0; ch < 16; ++ch) {
        float* bw = sb + (ch & 1) * BUFW;
        bw[loff[0]] = r0; bw[loff[1]] = r1; bw[loff[2]] = r2; bw[loff[3]] = r3;
        if (do5) bw[loff[4]] = r4;
        if (ch < 15) {
            const float* in2 = ib + (size_t)(ch + 1) * HW;
            r0 = in2[goff[0]]; r1 = in2[goff[1]]; r2 = in2[goff[2]]; r3 = in2[goff[3]];
            if (do5) r4 = in2[goff[4]];
        }
        float f[12];
        #pragma unroll
        for (int rr = 0; rr < 4; ++rr) {
            const float* br = bw + rr * SRW + l;
            f[rr * 3 + 0] = br[0];
            f[rr * 3 + 1] = br[1];
            f[rr * 3 + 2] = br[2];
        }
        float vA = accA[0] * f[0];
        float vB = accB[0] * f[3];
        vA = fmaf(accA[1], f[1],  vA);  vB = fmaf(accB[1], f[4],  vB);
        vA = fmaf(accA[2], f[2],  vA);  vB = fmaf(accB[2], f[5],  vB);
        vA = fmaf(accA[3], f[3],  vA);  vB = fmaf(accB[3], f[6],  vB);
        vA = fmaf(accA[4], f[4],  vA);  vB = fmaf(accB[4], f[7],  vB);
        vA = fmaf(accA[5], f[5],  vA);  vB = fmaf(accB[5], f[8],  vB);
        vA = fmaf(accA[6], f[6],  vA);  vB = fmaf(accB[6], f[9],  vB);
        vA = fmaf(accA[7], f[7],  vA);  vB = fmaf(accB[7], f[10], vB);
        vA = fmaf(accA[8], f[8],  vA);  vB = fmaf(accB[8], f[11], vB);
        ob[(size_t)ch * HW + oA] = vA;
        ob[(size_t)ch * HW + oB] = vB;
    }
}

extern "C" void kernel_launch(void* const* d_in, const int* in_sizes, int n_in,
                              void* d_out, int out_size, void* d_ws, size_t ws_size,
                              hipStream_t stream) {
    const float* features = (const float*)d_in[0];
    const float* inpt     = (const float*)d_in[1];
    const float* wgt      = (const float*)d_in[2];
    const float* bias     = (const float*)d_in[3];
    float* out            = (float*)d_out;

    const size_t WTAB_B = 18432;
    const size_t FF_B   = (size_t)BB * 9 * HW * 4;   // 9437184

    if (ws_size >= WTAB_B + FF_B) {
        uint4* wtab = (uint4*)d_ws;
        float* ff   = (float*)((char*)d_ws + WTAB_B);

        pff_prep<<<dim3(5), dim3(256), 0, stream>>>(wgt, wtab);

        dim3 g1(WW / 32, HH / 8, BB);   // (8, 32, 4) = 1024 blocks
        pff_conv<<<g1, dim3(512), 0, stream>>>(features, bias, wtab, ff);

        dim3 g2(WW / 64, HH / 4, BB);   // (4, 64, 4) = 1024 blocks
        pff_apply<<<g2, dim3(512), 0, stream>>>(inpt, ff, out);
    } else {
        dim3 grid(WW / 64, HH / 4, BB);
        dim3 block(512);
        pff_wave4<<<grid, block, 0, stream>>>(features, inpt, wgt, bias, out);
    }
}

// Round 13
// 78.529 us; speedup vs baseline: 1.0770x; 1.0770x over previous
//
#include <hip/hip_runtime.h>
#include <math.h>

// Problem constants (fixed by setup_inputs)
#define BB 4
#define NIC 64
#define CC 64
#define HH 256
#define WW 256
#define HW (HH * WW)

typedef short sh8 __attribute__((ext_vector_type(8)));    // 8 x bf16 MFMA frag
typedef float f32x4 __attribute__((ext_vector_type(4)));  // MFMA accum

// numpy/jax "reflect" (mirror, edge not repeated), pad=1
__device__ __forceinline__ int refl(int i, int n) {
    i = (i < 0) ? -i : i;
    return (i >= n) ? (2 * n - 2 - i) : i;
}
// fp32 -> bf16 round-to-nearest-even
__device__ __forceinline__ unsigned short f2bf(float v) {
    unsigned int x = __builtin_bit_cast(unsigned int, v);
    return (unsigned short)((x + 0x7FFFu + ((x >> 16) & 1u)) >> 16);
}

// ---- prep: weight A-fragments into d_ws (verified R11/R12) ------------------
__global__ void pff_prep(const float* __restrict__ wgt, uint4* __restrict__ wtab) {
    int e = blockIdx.x * 256 + threadIdx.x;
    if (e >= 1152) return;
    const int c = e >> 6, l = e & 63;
    const int p = c / 9, s = c - p * 9;
    const int tap = l & 15, kg = l >> 4;
    unsigned short h[8];
    #pragma unroll
    for (int j = 0; j < 8; ++j) {
        const int ni = 32 * p + 8 * kg + j;
        const float v = (tap <= 8) ? wgt[tap * 576 + ni * 9 + s] : 0.f;
        h[j] = f2bf(v);
    }
    uint4 o;
    o.x = h[0] | ((unsigned)h[1] << 16);
    o.y = h[2] | ((unsigned)h[3] << 16);
    o.z = h[4] | ((unsigned)h[5] << 16);
    o.w = h[6] | ((unsigned)h[7] << 16);
    wtab[e] = o;
}

// ---- fused kernel: MFMA conv + softmax (ff in LDS) + float4 apply -----------
// Tile 32w x 8h, 512 threads (8 waves).
// P1 == R12 pff_conv (verified): bf16 tile [10r][34c][32ni], 2 K-passes,
//   18 MFMA/wave, in-reg softmax; ff -> 9 KB LDS (no global round-trip).
// P2: lane owns 4 consecutive px (8 lanes/row x 8 rows); per ch: 3 x
//   (float4 + 2 edge dwords), 36 FMA, float4 store; wave does 8 ch;
//   depth-1 prefetch; NO LDS, NO barriers (G13: vectorized, DS-free).
// Resident blocks at different phases overlap MFMA/LDS vs VMEM/VALU pipes.
__global__ __launch_bounds__(512) void pff_fuse3(
    const float* __restrict__ features,
    const float* __restrict__ inpt,
    const float* __restrict__ bias,
    const uint4* __restrict__ wtab,
    float* __restrict__ out)
{
    __shared__ unsigned short FT[10 * 34 * 34];   // 23120 B
    __shared__ float ffl[9 * 256];                //  9216 B

    const int tid = threadIdx.x;
    const int wv  = __builtin_amdgcn_readfirstlane(tid >> 6);  // 0..7
    const int l   = tid & 63;
    const int pxl = l & 15, kg = l >> 4;
    const int W0 = blockIdx.x * 32, H0 = blockIdx.y * 8, b = blockIdx.z;

    // staging offsets (pass-invariant): 5440 packed b32 per pass, 11/thread
    int stg_g[11], stg_l[11];
    #pragma unroll
    for (int i = 0; i < 11; ++i) {
        const int flat = tid + 512 * i;
        const int nip = flat / 340;
        const int rc  = flat - nip * 340;
        const int r   = rc / 34, c2 = rc - r * 34;
        stg_l[i] = (flat < 5440) ? ((r * 34 + c2) * 34 + 2 * nip) : -1;
        stg_g[i] = refl(H0 - 1 + r, HH) * WW + refl(W0 - 1 + c2, WW)
                 + 2 * nip * HW;
    }

    f32x4 acc[2];
    acc[0] = (f32x4){0.f, 0.f, 0.f, 0.f};
    acc[1] = (f32x4){0.f, 0.f, 0.f, 0.f};

    #pragma unroll
    for (int p = 0; p < 2; ++p) {
        uint4 wf[9];   // weight frags: issued early, used after barrier
        #pragma unroll
        for (int s = 0; s < 9; ++s) wf[s] = wtab[(p * 9 + s) * 64 + l];

        const float* fp0 = features + ((size_t)b * NIC + 32 * p) * HW;
        #pragma unroll
        for (int i = 0; i < 11; ++i) {
            if (stg_l[i] >= 0) {
                const float* fp = fp0 + stg_g[i];
                const unsigned pk = f2bf(fp[0]) | ((unsigned)f2bf(fp[HW]) << 16);
                *(unsigned*)&FT[stg_l[i]] = pk;
            }
        }
        __syncthreads();   // tile pass p ready

        #pragma unroll
        for (int g = 0; g < 2; ++g) {
            #pragma unroll
            for (int s = 0; s < 9; ++s) {
                const int di = s / 3, dj = s - di * 3;
                const unsigned* q = (const unsigned*)
                    &FT[((wv + di) * 34 + pxl + 16 * g + dj) * 34 + kg * 8];
                uint4 bw;
                bw.x = q[0]; bw.y = q[1]; bw.z = q[2]; bw.w = q[3];
                acc[g] = __builtin_amdgcn_mfma_f32_16x16x32_bf16(
                    __builtin_bit_cast(sh8, wf[s]),
                    __builtin_bit_cast(sh8, bw), acc[g], 0, 0, 0);
            }
        }
        if (p == 0) __syncthreads();   // reads done before pass-1 overwrite
    }

    // softmax per group (taps on lanes pxl+{0,16,32,48}; verified R11/R12)
    float bv4[4];
    #pragma unroll
    for (int j = 0; j < 4; ++j) {
        const int tap = 4 * kg + j;
        bv4[j] = bias[tap <= 8 ? tap : 8];
    }
    #pragma unroll
    for (int g = 0; g < 2; ++g) {
        float lg[4]; bool val[4];
        #pragma unroll
        for (int j = 0; j < 4; ++j) {
            const int tap = 4 * kg + j;
            val[j] = (tap <= 8);
            lg[j] = acc[g][j] + bv4[j];
        }
        float ml = -3e38f;
        #pragma unroll
        for (int j = 0; j < 4; ++j) ml = fmaxf(ml, val[j] ? lg[j] : -3e38f);
        float m = fmaxf(ml, __shfl_xor(ml, 16));
        m = fmaxf(m, __shfl_xor(m, 32));
        float e[4], sl = 0.f;
        #pragma unroll
        for (int j = 0; j < 4; ++j) { e[j] = val[j] ? __expf(lg[j] - m) : 0.f; sl += e[j]; }
        float s = sl + __shfl_xor(sl, 16);
        s += __shfl_xor(s, 32);
        const float inv = 1.f / s;
        #pragma unroll
        for (int j = 0; j < 4; ++j) {
            const int tap = 4 * kg + j;
            if (val[j]) ffl[tap * 256 + wv * 32 + 16 * g + pxl] = e[j] * inv;
        }
    }
    __syncthreads();   // ffl complete

    // ================= P2: float4 apply (DS-free, barrier-free) ===============
    const int lr = l >> 3;            // tile row 0..7
    const int k4 = (l & 7) << 2;      // px col base 0,4,..,28

    float4 fq[9];                     // per-px filters: fq[t].{x,y,z,w} = px 0..3
    #pragma unroll
    for (int t = 0; t < 9; ++t)
        fq[t] = *(const float4*)&ffl[t * 256 + lr * 32 + k4];

    int gr[3];
    #pragma unroll
    for (int i = 0; i < 3; ++i) gr[i] = refl(H0 + lr - 1 + i, HH) * WW;
    const int c0 = W0 + k4;
    const int cL = refl(c0 - 1, WW);
    const int cR = refl(c0 + 4, WW);

    const float* ip = inpt + ((size_t)b * CC + wv * 8) * HW;
    float* op = out + ((size_t)b * CC + wv * 8) * HW + (size_t)(H0 + lr) * WW + c0;

    float4 v0 = *(const float4*)&ip[gr[0] + c0];
    float4 v1 = *(const float4*)&ip[gr[1] + c0];
    float4 v2 = *(const float4*)&ip[gr[2] + c0];
    float e0 = ip[gr[0] + cL], e1 = ip[gr[1] + cL], e2 = ip[gr[2] + cL];
    float d0 = ip[gr[0] + cR], d1 = ip[gr[1] + cR], d2 = ip[gr[2] + cR];

    for (int ch = 0; ch < 8; ++ch) {
        float4 n0, n1, n2; float m0, m1, m2, p0, p1, p2;
        if (ch < 7) {   // depth-1 prefetch: stays in flight under the FMAs
            const float* i2 = ip + (size_t)(ch + 1) * HW;
            n0 = *(const float4*)&i2[gr[0] + c0];
            n1 = *(const float4*)&i2[gr[1] + c0];
            n2 = *(const float4*)&i2[gr[2] + c0];
            m0 = i2[gr[0] + cL]; m1 = i2[gr[1] + cL]; m2 = i2[gr[2] + cL];
            p0 = i2[gr[0] + cR]; p1 = i2[gr[1] + cR]; p2 = i2[gr[2] + cR];
        }

        float4 o;
        // px0: cols c0-1, c0, c0+1
        o.x =      fq[0].x * e0;
        o.x = fmaf(fq[1].x, v0.x, o.x);
        o.x = fmaf(fq[2].x, v0.y, o.x);
        o.x = fmaf(fq[3].x, e1,   o.x);
        o.x = fmaf(fq[4].x, v1.x, o.x);
        o.x = fmaf(fq[5].x, v1.y, o.x);
        o.x = fmaf(fq[6].x, e2,   o.x);
        o.x = fmaf(fq[7].x, v2.x, o.x);
        o.x = fmaf(fq[8].x, v2.y, o.x);
        // px1
        o.y =      fq[0].y * v0.x;
        o.y = fmaf(fq[1].y, v0.y, o.y);
        o.y = fmaf(fq[2].y, v0.z, o.y);
        o.y = fmaf(fq[3].y, v1.x, o.y);
        o.y = fmaf(fq[4].y, v1.y, o.y);
        o.y = fmaf(fq[5].y, v1.z, o.y);
        o.y = fmaf(fq[6].y, v2.x, o.y);
        o.y = fmaf(fq[7].y, v2.y, o.y);
        o.y = fmaf(fq[8].y, v2.z, o.y);
        // px2
        o.z =      fq[0].z * v0.y;
        o.z = fmaf(fq[1].z, v0.z, o.z);
        o.z = fmaf(fq[2].z, v0.w, o.z);
        o.z = fmaf(fq[3].z, v1.y, o.z);
        o.z = fmaf(fq[4].z, v1.z, o.z);
        o.z = fmaf(fq[5].z, v1.w, o.z);
        o.z = fmaf(fq[6].z, v2.y, o.z);
        o.z = fmaf(fq[7].z, v2.z, o.z);
        o.z = fmaf(fq[8].z, v2.w, o.z);
        // px3: cols c0+2, c0+3, c0+4
        o.w =      fq[0].w * v0.z;
        o.w = fmaf(fq[1].w, v0.w, o.w);
        o.w = fmaf(fq[2].w, d0,   o.w);
        o.w = fmaf(fq[3].w, v1.z, o.w);
        o.w = fmaf(fq[4].w, v1.w, o.w);
        o.w = fmaf(fq[5].w, d1,   o.w);
        o.w = fmaf(fq[6].w, v2.z, o.w);
        o.w = fmaf(fq[7].w, v2.w, o.w);
        o.w = fmaf(fq[8].w, d2,   o.w);

        *(float4*)&op[(size_t)ch * HW] = o;

        if (ch < 7) {
            v0 = n0; v1 = n1; v2 = n2;
            e0 = m0; e1 = m1; e2 = m2;
            d0 = p0; d1 = p1; d2 = p2;
        }
    }
}

extern "C" void kernel_launch(void* const* d_in, const int* in_sizes, int n_in,
                              void* d_out, int out_size, void* d_ws, size_t ws_size,
                              hipStream_t stream) {
    const float* features = (const float*)d_in[0];
    const float* inpt     = (const float*)d_in[1];
    const float* wgt      = (const float*)d_in[2];
    const float* bias     = (const float*)d_in[3];
    float* out            = (float*)d_out;
    uint4* wtab           = (uint4*)d_ws;   // 18432 B scratch

    pff_prep<<<dim3(5), dim3(256), 0, stream>>>(wgt, wtab);

    dim3 grid(WW / 32, HH / 8, BB);   // (8, 32, 4) = 1024 blocks
    dim3 block(512);
    pff_fuse3<<<grid, block, 0, stream>>>(features, inpt, bias, wtab, out);
}

// Round 15
// 71.472 us; speedup vs baseline: 1.1833x; 1.0987x over previous
//
#include <hip/hip_runtime.h>
#include <math.h>

// Problem constants (fixed by setup_inputs)
#define BB 4
#define NIC 64
#define CC 64
#define HH 256
#define WW 256
#define HW (HH * WW)

#define SRW 68          // padded stencil row stride (66 used) — R10 proven
#define BUFW 272        // 4 rows * 68 floats per strip buffer

// numpy/jax "reflect" (mirror, edge not repeated), pad=1
__device__ __forceinline__ int refl(int i, int n) {
    i = (i < 0) ? -i : i;
    return (i >= n) ? (2 * n - 2 - i) : i;
}

// R15 = R10 champion (70.4 us, proven) + R9's unroll-2 A/B DOUBLE-BUFFERED
// depth-2 prefetch pattern (proven correct in R9). R14 lesson: the
// single-shared-buffer variant breaks correctness — keep per-sub-iteration
// double buffering. No swizzle (single-variable discipline).
// Lessons kept: no reg cap (R2), scalarized wave idx (R3), wave-private
// barrier-free loops (R7), 4-way split = 32 waves/CU (R10), VGPR must stay
// <= 64 (R9: 84 VGPR halves occupancy).
__global__ __launch_bounds__(512) void pff_d2b(
    const float* __restrict__ features,
    const float* __restrict__ inpt,
    const float* __restrict__ wgt,
    const float* __restrict__ bias,
    float* __restrict__ out)
{
    __shared__ float stage[8][2 * BUFW];      // 17408 B, per-wave private
    __shared__ float part[4][9][128];         // 18432 B, combine only

    const int tid  = threadIdx.x;
    const int wv   = __builtin_amdgcn_readfirstlane(tid >> 6);  // 0..7 scalar
    const int q    = wv >> 1;                 // channel quarter 0..3
    const int tr   = wv & 1;                  // row-wave 0..1
    const int l    = tid & 63;
    const int p    = tid & 127;               // (tr,lane) slot
    const int W0 = blockIdx.x * 64;
    const int H0 = blockIdx.y * 4;
    const int b  = blockIdx.z;

    // per-wave stencil strip: global rows H0+2tr-1 .. +2, cols W0-1..W0+64
    int goff[5], loff[5];
    #pragma unroll
    for (int t = 0; t < 5; ++t) {
        const int e = (t < 4) ? (l + 64 * t) : (256 + (l & 7));
        const int row = e / 66, col = e - row * 66;
        loff[t] = row * SRW + col;
        goff[t] = refl(H0 + 2 * tr - 1 + row, HH) * WW + refl(W0 - 1 + col, WW);
    }
    const bool do5 = (l < 8);

    float accA[9], accB[9];
    #pragma unroll
    for (int k = 0; k < 9; ++k) { accA[k] = 0.f; accB[k] = 0.f; }

    float* sb = &stage[wv][0];

    // ============ Phase 1: conv partials, 16 ch, unroll-2 A/B, dbuf ==========
    const float* fb = features + (size_t)b * NIC * HW + (size_t)q * 16 * HW;
    float A0 = fb[goff[0]], A1 = fb[goff[1]], A2 = fb[goff[2]], A3 = fb[goff[3]];
    float A4 = do5 ? fb[goff[4]] : 0.f;
    const float* fb1 = fb + HW;
    float B0 = fb1[goff[0]], B1 = fb1[goff[1]], B2 = fb1[goff[2]], B3 = fb1[goff[3]];
    float B4 = do5 ? fb1[goff[4]] : 0.f;

    for (int ni = 0; ni < 16; ni += 2) {
        // ---- even: buffer 0, consume set A (ch ni), refill A <- ch ni+2 ----
        {
            float* bw = sb;
            bw[loff[0]] = A0; bw[loff[1]] = A1; bw[loff[2]] = A2; bw[loff[3]] = A3;
            if (do5) bw[loff[4]] = A4;
            if (ni + 2 < 16) {        // ~10 loads in flight at steady state
                const float* fn = fb + (size_t)(ni + 2) * HW;
                A0 = fn[goff[0]]; A1 = fn[goff[1]]; A2 = fn[goff[2]]; A3 = fn[goff[3]];
                if (do5) A4 = fn[goff[4]];
            }
            float f[12];
            #pragma unroll
            for (int rr = 0; rr < 4; ++rr) {   // same-wave DS: in-order
                const float* br = bw + rr * SRW + l;
                f[rr * 3 + 0] = br[0];
                f[rr * 3 + 1] = br[1];
                f[rr * 3 + 2] = br[2];
            }
            const float* wn = wgt + (q * 16 + ni) * 9;   // scalar -> s_load
            #pragma unroll
            for (int k = 0; k < 9; ++k) {
                const float* wk = wn + k * (NIC * 9);
                const float w0 = wk[0], w1 = wk[1], w2 = wk[2];
                const float w3 = wk[3], w4 = wk[4], w5 = wk[5];
                const float w6 = wk[6], w7 = wk[7], w8 = wk[8];
                accA[k] = fmaf(f[0],  w0, accA[k]);
                accB[k] = fmaf(f[3],  w0, accB[k]);
                accA[k] = fmaf(f[1],  w1, accA[k]);
                accB[k] = fmaf(f[4],  w1, accB[k]);
                accA[k] = fmaf(f[2],  w2, accA[k]);
                accB[k] = fmaf(f[5],  w2, accB[k]);
                accA[k] = fmaf(f[3],  w3, accA[k]);
                accB[k] = fmaf(f[6],  w3, accB[k]);
                accA[k] = fmaf(f[4],  w4, accA[k]);
                accB[k] = fmaf(f[7],  w4, accB[k]);
                accA[k] = fmaf(f[5],  w5, accA[k]);
                accB[k] = fmaf(f[8],  w5, accB[k]);
                accA[k] = fmaf(f[6],  w6, accA[k]);
                accB[k] = fmaf(f[9],  w6, accB[k]);
                accA[k] = fmaf(f[7],  w7, accA[k]);
                accB[k] = fmaf(f[10], w7, accB[k]);
                accA[k] = fmaf(f[8],  w8, accA[k]);
                accB[k] = fmaf(f[11], w8, accB[k]);
            }
        }
        // ---- odd: buffer 1, consume set B (ch ni+1), refill B <- ch ni+3 ----
        {
            float* bw = sb + BUFW;
            bw[loff[0]] = B0; bw[loff[1]] = B1; bw[loff[2]] = B2; bw[loff[3]] = B3;
            if (do5) bw[loff[4]] = B4;
            if (ni + 3 < 16) {
                const float* fn = fb + (size_t)(ni + 3) * HW;
                B0 = fn[goff[0]]; B1 = fn[goff[1]]; B2 = fn[goff[2]]; B3 = fn[goff[3]];
                if (do5) B4 = fn[goff[4]];
            }
            float f[12];
            #pragma unroll
            for (int rr = 0; rr < 4; ++rr) {
                const float* br = bw + rr * SRW + l;
                f[rr * 3 + 0] = br[0];
                f[rr * 3 + 1] = br[1];
                f[rr * 3 + 2] = br[2];
            }
            const float* wn = wgt + (q * 16 + ni + 1) * 9;
            #pragma unroll
            for (int k = 0; k < 9; ++k) {
                const float* wk = wn + k * (NIC * 9);
                const float w0 = wk[0], w1 = wk[1], w2 = wk[2];
                const float w3 = wk[3], w4 = wk[4], w5 = wk[5];
                const float w6 = wk[6], w7 = wk[7], w8 = wk[8];
                accA[k] = fmaf(f[0],  w0, accA[k]);
                accB[k] = fmaf(f[3],  w0, accB[k]);
                accA[k] = fmaf(f[1],  w1, accA[k]);
                accB[k] = fmaf(f[4],  w1, accB[k]);
                accA[k] = fmaf(f[2],  w2, accA[k]);
                accB[k] = fmaf(f[5],  w2, accB[k]);
                accA[k] = fmaf(f[3],  w3, accA[k]);
                accB[k] = fmaf(f[6],  w3, accB[k]);
                accA[k] = fmaf(f[4],  w4, accA[k]);
                accB[k] = fmaf(f[7],  w4, accB[k]);
                accA[k] = fmaf(f[5],  w5, accA[k]);
                accB[k] = fmaf(f[8],  w5, accB[k]);
                accA[k] = fmaf(f[6],  w6, accA[k]);
                accB[k] = fmaf(f[9],  w6, accB[k]);
                accA[k] = fmaf(f[7],  w7, accA[k]);
                accB[k] = fmaf(f[10], w7, accB[k]);
                accA[k] = fmaf(f[8],  w8, accA[k]);
                accB[k] = fmaf(f[11], w8, accB[k]);
            }
        }
    }

    // prefetch P2 channels 0,1 now; latency hides under combine/softmax (T14)
    const float* ib = inpt + (size_t)b * CC * HW + (size_t)q * 16 * HW;
    A0 = ib[goff[0]]; A1 = ib[goff[1]]; A2 = ib[goff[2]]; A3 = ib[goff[3]];
    if (do5) A4 = ib[goff[4]];
    const float* ib1 = ib + HW;
    B0 = ib1[goff[0]]; B1 = ib1[goff[1]]; B2 = ib1[goff[2]]; B3 = ib1[goff[3]];
    if (do5) B4 = ib1[goff[4]];

    // ============ combine quarters + softmax (one-time barriers) =============
    #pragma unroll
    for (int k = 0; k < 9; ++k) part[q][k][p] = accA[k];
    __syncthreads();
    #pragma unroll
    for (int k = 0; k < 9; ++k)
        accA[k] = part[0][k][p] + part[1][k][p] + part[2][k][p] + part[3][k][p]
                + bias[k];
    __syncthreads();
    #pragma unroll
    for (int k = 0; k < 9; ++k) part[q][k][p] = accB[k];
    __syncthreads();
    #pragma unroll
    for (int k = 0; k < 9; ++k)
        accB[k] = part[0][k][p] + part[1][k][p] + part[2][k][p] + part[3][k][p]
                + bias[k];

    {
        float m = accA[0];
        #pragma unroll
        for (int k = 1; k < 9; ++k) m = fmaxf(m, accA[k]);
        float s = 0.f;
        #pragma unroll
        for (int k = 0; k < 9; ++k) { accA[k] = __expf(accA[k] - m); s += accA[k]; }
        const float inv = 1.f / s;
        #pragma unroll
        for (int k = 0; k < 9; ++k) accA[k] *= inv;
    }
    {
        float m = accB[0];
        #pragma unroll
        for (int k = 1; k < 9; ++k) m = fmaxf(m, accB[k]);
        float s = 0.f;
        #pragma unroll
        for (int k = 0; k < 9; ++k) { accB[k] = __expf(accB[k] - m); s += accB[k]; }
        const float inv = 1.f / s;
        #pragma unroll
        for (int k = 0; k < 9; ++k) accB[k] *= inv;
    }

    // ============ Phase 2: apply, 16 ch, unroll-2 A/B, dbuf, barrier-free =====
    float* ob = out + (size_t)b * CC * HW + (size_t)q * 16 * HW;
    const int oA = (H0 + 2 * tr) * WW + W0 + l;
    const int oB = oA + WW;

    for (int ch = 0; ch < 16; ch += 2) {
        // ---- even: buffer 0, consume A (ch), refill A <- ch+2 ----
        {
            float* bw = sb;
            bw[loff[0]] = A0; bw[loff[1]] = A1; bw[loff[2]] = A2; bw[loff[3]] = A3;
            if (do5) bw[loff[4]] = A4;
            if (ch + 2 < 16) {
                const float* in2 = ib + (size_t)(ch + 2) * HW;
                A0 = in2[goff[0]]; A1 = in2[goff[1]]; A2 = in2[goff[2]]; A3 = in2[goff[3]];
                if (do5) A4 = in2[goff[4]];
            }
            float f[12];
            #pragma unroll
            for (int rr = 0; rr < 4; ++rr) {
                const float* br = bw + rr * SRW + l;
                f[rr * 3 + 0] = br[0];
                f[rr * 3 + 1] = br[1];
                f[rr * 3 + 2] = br[2];
            }
            float vA = accA[0] * f[0];
            float vB = accB[0] * f[3];
            vA = fmaf(accA[1], f[1],  vA);  vB = fmaf(accB[1], f[4],  vB);
            vA = fmaf(accA[2], f[2],  vA);  vB = fmaf(accB[2], f[5],  vB);
            vA = fmaf(accA[3], f[3],  vA);  vB = fmaf(accB[3], f[6],  vB);
            vA = fmaf(accA[4], f[4],  vA);  vB = fmaf(accB[4], f[7],  vB);
            vA = fmaf(accA[5], f[5],  vA);  vB = fmaf(accB[5], f[8],  vB);
            vA = fmaf(accA[6], f[6],  vA);  vB = fmaf(accB[6], f[9],  vB);
            vA = fmaf(accA[7], f[7],  vA);  vB = fmaf(accB[7], f[10], vB);
            vA = fmaf(accA[8], f[8],  vA);  vB = fmaf(accB[8], f[11], vB);
            ob[(size_t)ch * HW + oA] = vA;
            ob[(size_t)ch * HW + oB] = vB;
        }
        // ---- odd: buffer 1, consume B (ch+1), refill B <- ch+3 ----
        {
            float* bw = sb + BUFW;
            bw[loff[0]] = B0; bw[loff[1]] = B1; bw[loff[2]] = B2; bw[loff[3]] = B3;
            if (do5) bw[loff[4]] = B4;
            if (ch + 3 < 16) {
                const float* in2 = ib + (size_t)(ch + 3) * HW;
                B0 = in2[goff[0]]; B1 = in2[goff[1]]; B2 = in2[goff[2]]; B3 = in2[goff[3]];
                if (do5) B4 = in2[goff[4]];
            }
            float f[12];
            #pragma unroll
            for (int rr = 0; rr < 4; ++rr) {
                const float* br = bw + rr * SRW + l;
                f[rr * 3 + 0] = br[0];
                f[rr * 3 + 1] = br[1];
                f[rr * 3 + 2] = br[2];
            }
            float vA = accA[0] * f[0];
            float vB = accB[0] * f[3];
            vA = fmaf(accA[1], f[1],  vA);  vB = fmaf(accB[1], f[4],  vB);
            vA = fmaf(accA[2], f[2],  vA);  vB = fmaf(accB[2], f[5],  vB);
            vA = fmaf(accA[3], f[3],  vA);  vB = fmaf(accB[3], f[6],  vB);
            vA = fmaf(accA[4], f[4],  vA);  vB = fmaf(accB[4], f[7],  vB);
            vA = fmaf(accA[5], f[5],  vA);  vB = fmaf(accB[5], f[8],  vB);
            vA = fmaf(accA[6], f[6],  vA);  vB = fmaf(accB[6], f[9],  vB);
            vA = fmaf(accA[7], f[7],  vA);  vB = fmaf(accB[7], f[10], vB);
            vA = fmaf(accA[8], f[8],  vA);  vB = fmaf(accB[8], f[11], vB);
            ob[(size_t)(ch + 1) * HW + oA] = vA;
            ob[(size_t)(ch + 1) * HW + oB] = vB;
        }
    }
}

extern "C" void kernel_launch(void* const* d_in, const int* in_sizes, int n_in,
                              void* d_out, int out_size, void* d_ws, size_t ws_size,
                              hipStream_t stream) {
    const float* features = (const float*)d_in[0];
    const float* inpt     = (const float*)d_in[1];
    const float* wgt      = (const float*)d_in[2];
    const float* bias     = (const float*)d_in[3];
    float* out            = (float*)d_out;

    dim3 grid(WW / 64, HH / 4, BB);   // (4, 64, 4) = 1024 blocks, 4/CU
    dim3 block(512);
    pff_d2b<<<grid, block, 0, stream>>>(features, inpt, wgt, bias, out);
}